// Round 6
// baseline (29.719 us; speedup 1.0000x reference)
//
#include <hip/hip_runtime.h>

#define BATCH 4096
#define IN_DIM 512
#define OUT_DIM 512
#define NK 4
#define SX (IN_DIM + NK)   // 516 floats per x row
#define BMR 256            // rows per block
#define BNC 32             // cols per block

typedef short bf16x8 __attribute__((ext_vector_type(8)));
typedef float f32x4 __attribute__((ext_vector_type(4)));

__device__ __forceinline__ unsigned short f2bf(float f) {
    unsigned int u = __float_as_uint(f);
    u = u + 0x7FFFu + ((u >> 16) & 1u);   // round-to-nearest-even
    return (unsigned short)(u >> 16);
}

__device__ __forceinline__ void gload_lds16(const void* g, void* l) {
    __builtin_amdgcn_global_load_lds(
        (const __attribute__((address_space(1))) void*)g,
        (__attribute__((address_space(3))) void*)l, 16, 0, 0);
}

// ---------------- kernel 1: fp32 -> bf16 pre-pass ----------------
__global__ __launch_bounds__(256) void convert_kernel(
    const float* __restrict__ x, const float* __restrict__ w,
    unsigned short* __restrict__ wb, unsigned short* __restrict__ fb)
{
    const int WCH = NK * OUT_DIM * IN_DIM / 4;   // 262144 float4 chunks of W
    int g = blockIdx.x * 256 + threadIdx.x;
    if (g < WCH) {
        const float4 v = reinterpret_cast<const float4*>(w)[g];
        unsigned short h[4] = {f2bf(v.x), f2bf(v.y), f2bf(v.z), f2bf(v.w)};
        *reinterpret_cast<uint2*>(&wb[g * 4]) = *reinterpret_cast<const uint2*>(h);
    } else {
        int idx = g - WCH;                        // feat chunks: 4096*128
        int row = idx >> 7;
        int c   = (idx & 127) * 4;
        const float4 v = *reinterpret_cast<const float4*>(&x[(size_t)row * SX + c]);
        unsigned short h[4] = {f2bf(v.x), f2bf(v.y), f2bf(v.z), f2bf(v.w)};
        *reinterpret_cast<uint2*>(&fb[row * IN_DIM + c]) = *reinterpret_cast<const uint2*>(h);
    }
}

// ------- kernel 2: barrier-free K-loop GEMM -------
// Block = 256 rows x 32 cols x 4 knots. B (4x32x512 bf16 = 128 KB) staged in LDS
// ONCE; K-loop has NO barriers: A streams global->VGPR, B from LDS, MFMA.
// 8 waves (512 thr), each owns 32 rows; grid 16x16 = 256 blocks = 1/CU.
__global__ __launch_bounds__(512, 2) void mpl_gemm(
    const unsigned short* __restrict__ fb,   // (4096,512) bf16
    const unsigned short* __restrict__ wb,   // (4,512,512) bf16
    const float* __restrict__ x,             // (4096,516) fp32 (for p)
    const float* __restrict__ bias,          // (4,512)
    float* __restrict__ out)                 // (4096,512)
{
    __shared__ unsigned short Bs[NK * BNC * IN_DIM];   // 128 KB, swizzled content

    const int tid  = threadIdx.x;          // 0..511
    const int lane = tid & 63;
    const int wid  = tid >> 6;             // 0..7
    const int wr   = wid * 32;             // wave's row offset in block tile
    const int R0   = blockIdx.x * BMR;
    const int C0   = blockIdx.y * BNC;

    // ---- stage ALL of B once: 8192 chunks of 16B; dest linear, src chunk-permuted ----
    #pragma unroll
    for (int j = 0; j < 16; ++j) {
        int ch  = j * 512 + tid;
        int gr  = ch >> 6;                 // (kn*32 + col), 0..127
        int c   = ch & 63;                 // 16B chunk within 1KB row
        int kn  = gr >> 5;
        int col = gr & 31;
        gload_lds16(wb + (size_t)kn * OUT_DIM * IN_DIM + (size_t)(C0 + col) * IN_DIM
                       + ((c ^ (col & 7)) << 3),
                    &Bs[ch * 8]);
    }
    __syncthreads();   // one full drain; B resident for the rest of the kernel

    f32x4 acc[NK][2][2] = {};
    const int cl = lane & 15;
    const int kb = (lane >> 4) * 8;

    // ---- barrier-free K-loop: 16 steps of K=32 ----
    #pragma unroll
    for (int kx = 0; kx < IN_DIM / 32; ++kx) {
        const int k0 = kx * 32;
        bf16x8 af[2];
        #pragma unroll
        for (int m = 0; m < 2; ++m)
            af[m] = *reinterpret_cast<const bf16x8*>(
                &fb[(size_t)(R0 + wr + m * 16 + cl) * IN_DIM + k0 + kb]);
        #pragma unroll
        for (int kn = 0; kn < NK; ++kn) {
            bf16x8 bfr[2];
            #pragma unroll
            for (int n = 0; n < 2; ++n) {
                int col  = n * 16 + cl;
                int boff = (((kn * BNC + col) * IN_DIM + k0 + kb) * 2) ^ ((col & 7) << 4);
                bfr[n] = *reinterpret_cast<const bf16x8*>(
                    reinterpret_cast<const char*>(Bs) + boff);
            }
            __builtin_amdgcn_s_setprio(1);
            #pragma unroll
            for (int m = 0; m < 2; ++m)
                #pragma unroll
                for (int n = 0; n < 2; ++n)
                    acc[kn][m][n] = __builtin_amdgcn_mfma_f32_16x16x32_bf16(
                        af[m], bfr[n], acc[kn][m][n], 0, 0, 0);
            __builtin_amdgcn_s_setprio(0);
        }
    }

    // ---- epilogue: res = sum_k p[b,k]*(acc_k + bias_k[o]); elu ----
    const int rl = (lane >> 4) * 4;
    float bcol[2][NK];
    #pragma unroll
    for (int n = 0; n < 2; ++n)
        #pragma unroll
        for (int k = 0; k < NK; ++k)
            bcol[n][k] = bias[k * OUT_DIM + C0 + n * 16 + cl];

    #pragma unroll
    for (int m = 0; m < 2; ++m) {
        #pragma unroll
        for (int r = 0; r < 4; ++r) {
            const int row = R0 + wr + m * 16 + rl + r;
            const float4 p = *reinterpret_cast<const float4*>(&x[(size_t)row * SX + IN_DIM]);
            const float pk[4] = {p.x, p.y, p.z, p.w};
            #pragma unroll
            for (int n = 0; n < 2; ++n) {
                float v = 0.f;
                #pragma unroll
                for (int k = 0; k < NK; ++k)
                    v += pk[k] * (acc[k][m][n][r] + bcol[n][k]);
                v = (v > 0.f) ? v : expm1f(v);
                out[(size_t)row * OUT_DIM + C0 + n * 16 + cl] = v;
            }
        }
    }
}

// ---------------- fallback (round-1 kernel) if ws too small ----------------
#define LDT 72
__global__ __launch_bounds__(256) void mpl_kernel_fb(
    const float* __restrict__ x, const float* __restrict__ w,
    const float* __restrict__ bias, float* __restrict__ out)
{
    __shared__ unsigned short Asf[64][LDT];
    __shared__ unsigned short Bsf[NK][64][LDT];
    const int tid = threadIdx.x, lane = tid & 63, wid = tid >> 6;
    const int wr = (wid >> 1) * 32, wc = (wid & 1) * 32;
    const int R0 = blockIdx.x * 64, C0 = blockIdx.y * 64;
    f32x4 acc[NK][2][2] = {};
    const int cl = lane & 15, kb = (lane >> 4) * 8;
    for (int kt = 0; kt < IN_DIM / 64; ++kt) {
        const int k0 = kt * 64;
        __syncthreads();
        #pragma unroll
        for (int j = 0; j < 4; ++j) {
            int f = tid + 256 * j, row = f >> 4, c4 = (f & 15) * 4;
            const float4 v = *reinterpret_cast<const float4*>(&x[(size_t)(R0 + row) * SX + k0 + c4]);
            unsigned short h[4] = {f2bf(v.x), f2bf(v.y), f2bf(v.z), f2bf(v.w)};
            *reinterpret_cast<uint2*>(&Asf[row][c4]) = *reinterpret_cast<const uint2*>(h);
        }
        #pragma unroll
        for (int kn = 0; kn < NK; ++kn)
            #pragma unroll
            for (int j = 0; j < 4; ++j) {
                int f = tid + 256 * j, row = f >> 4, c4 = (f & 15) * 4;
                const float4 v = *reinterpret_cast<const float4*>(
                    &w[(size_t)kn * OUT_DIM * IN_DIM + (size_t)(C0 + row) * IN_DIM + k0 + c4]);
                unsigned short h[4] = {f2bf(v.x), f2bf(v.y), f2bf(v.z), f2bf(v.w)};
                *reinterpret_cast<uint2*>(&Bsf[kn][row][c4]) = *reinterpret_cast<const uint2*>(h);
            }
        __syncthreads();
        #pragma unroll
        for (int kk = 0; kk < 64; kk += 32) {
            bf16x8 af[2];
            #pragma unroll
            for (int m = 0; m < 2; ++m)
                af[m] = *reinterpret_cast<const bf16x8*>(&Asf[wr + m * 16 + cl][kk + kb]);
            #pragma unroll
            for (int kn = 0; kn < NK; ++kn) {
                bf16x8 bfr[2];
                #pragma unroll
                for (int n = 0; n < 2; ++n)
                    bfr[n] = *reinterpret_cast<const bf16x8*>(&Bsf[kn][wc + n * 16 + cl][kk + kb]);
                #pragma unroll
                for (int m = 0; m < 2; ++m)
                    #pragma unroll
                    for (int n = 0; n < 2; ++n)
                        acc[kn][m][n] = __builtin_amdgcn_mfma_f32_16x16x32_bf16(
                            af[m], bfr[n], acc[kn][m][n], 0, 0, 0);
            }
        }
    }
    const int rl = (lane >> 4) * 4;
    float bcol[2][NK];
    #pragma unroll
    for (int n = 0; n < 2; ++n)
        #pragma unroll
        for (int k = 0; k < NK; ++k)
            bcol[n][k] = bias[k * OUT_DIM + C0 + wc + n * 16 + cl];
    #pragma unroll
    for (int m = 0; m < 2; ++m)
        #pragma unroll
        for (int r = 0; r < 4; ++r) {
            const int row = R0 + wr + m * 16 + rl + r;
            const float4 p = *reinterpret_cast<const float4*>(&x[(size_t)row * SX + IN_DIM]);
            const float pk[4] = {p.x, p.y, p.z, p.w};
            #pragma unroll
            for (int n = 0; n < 2; ++n) {
                float v = 0.f;
                #pragma unroll
                for (int k = 0; k < NK; ++k)
                    v += pk[k] * (acc[k][m][n][r] + bcol[n][k]);
                v = (v > 0.f) ? v : expm1f(v);
                out[(size_t)row * OUT_DIM + C0 + wc + n * 16 + cl] = v;
            }
        }
}

extern "C" void kernel_launch(void* const* d_in, const int* in_sizes, int n_in,
                              void* d_out, int out_size, void* d_ws, size_t ws_size,
                              hipStream_t stream) {
    const float* x    = (const float*)d_in[0];
    const float* w    = (const float*)d_in[1];
    const float* bias = (const float*)d_in[2];
    float* out        = (float*)d_out;

    const size_t wb_bytes = (size_t)NK * OUT_DIM * IN_DIM * 2;   // 2 MB
    const size_t fb_bytes = (size_t)BATCH * IN_DIM * 2;          // 4 MB

    if (ws_size < wb_bytes + fb_bytes) {
        dim3 grid(BATCH / 64, OUT_DIM / 64);
        mpl_kernel_fb<<<grid, dim3(256), 0, stream>>>(x, w, bias, out);
        return;
    }

    unsigned short* wb = (unsigned short*)d_ws;
    unsigned short* fb = (unsigned short*)((char*)d_ws + wb_bytes);

    const int total_chunks = NK * OUT_DIM * IN_DIM / 4 + BATCH * IN_DIM / 4;  // 786432
    convert_kernel<<<dim3(total_chunks / 256), dim3(256), 0, stream>>>(x, w, wb, fb);

    dim3 grid(BATCH / BMR, OUT_DIM / BNC);   // 16 x 16
    mpl_gemm<<<grid, dim3(512), 0, stream>>>(fb, wb, x, bias, out);
}

// Round 7
// 28.930 us; speedup vs baseline: 1.0273x; 1.0273x over previous
//
#include <hip/hip_runtime.h>

#define BATCH 4096
#define IN_DIM 512
#define OUT_DIM 512
#define NK 4
#define SX (IN_DIM + NK)   // 516 floats per x row
#define BM 64
#define BN 64
#define BK 64
#define KT (IN_DIM / BK)   // 8 K-tiles

typedef short bf16x8 __attribute__((ext_vector_type(8)));
typedef float f32x4 __attribute__((ext_vector_type(4)));

__device__ __forceinline__ unsigned short f2bf(float f) {
    unsigned int u = __float_as_uint(f);
    u = u + 0x7FFFu + ((u >> 16) & 1u);   // round-to-nearest-even
    return (unsigned short)(u >> 16);
}

__device__ __forceinline__ void gload_lds16(const void* g, void* l) {
    __builtin_amdgcn_global_load_lds(
        (const __attribute__((address_space(1))) void*)g,
        (__attribute__((address_space(3))) void*)l, 16, 0, 0);
}

// ---------------- kernel 1: fp32 -> bf16 pre-pass ----------------
__global__ __launch_bounds__(256) void convert_kernel(
    const float* __restrict__ x, const float* __restrict__ w,
    unsigned short* __restrict__ wb, unsigned short* __restrict__ fb)
{
    const int WCH = NK * OUT_DIM * IN_DIM / 4;   // 262144 float4 chunks of W
    int g = blockIdx.x * 256 + threadIdx.x;
    if (g < WCH) {
        const float4 v = reinterpret_cast<const float4*>(w)[g];
        unsigned short h[4] = {f2bf(v.x), f2bf(v.y), f2bf(v.z), f2bf(v.w)};
        *reinterpret_cast<uint2*>(&wb[g * 4]) = *reinterpret_cast<const uint2*>(h);
    } else {
        int idx = g - WCH;                        // feat chunks: 4096*128
        int row = idx >> 7;
        int c   = (idx & 127) * 4;
        const float4 v = *reinterpret_cast<const float4*>(&x[(size_t)row * SX + c]);
        unsigned short h[4] = {f2bf(v.x), f2bf(v.y), f2bf(v.z), f2bf(v.w)};
        *reinterpret_cast<uint2*>(&fb[row * IN_DIM + c]) = *reinterpret_cast<const uint2*>(h);
    }
}

// ------- kernel 2: counted-vmcnt pipelined GEMM + XCD-column affinity -------
// 1-D grid of 512 blocks. xcd = bid&7 selects the OUTPUT COLUMN tile, so all
// 64 row-blocks sharing one 2MB B-column-tile land on the same XCD and share
// its 4MB L2 (B LLC traffic 128MB -> 16MB).
__global__ __launch_bounds__(256) void mpl_gemm(
    const unsigned short* __restrict__ fb,   // (4096,512) bf16
    const unsigned short* __restrict__ wb,   // (4,512,512) bf16
    const float* __restrict__ x,             // (4096,516) fp32 (for p)
    const float* __restrict__ bias,          // (4,512)
    float* __restrict__ out)                 // (4096,512)
{
    __shared__ unsigned short As[2 * BM * BK];        // 2 x 8 KB
    __shared__ unsigned short Bs[2 * NK * BN * BK];   // 2 x 32 KB

    const int tid  = threadIdx.x;
    const int lane = tid & 63;
    const int wid  = tid >> 6;
    const int wr   = (wid >> 1) * 32;
    const int wc   = (wid & 1) * 32;
    const int bid  = blockIdx.x;
    const int R0   = (bid >> 3) * BM;      // 64 row-tiles per column
    const int C0   = (bid & 7) * BN;       // column == XCD (round-robin dispatch)

    f32x4 acc[NK][2][2] = {};
    const int cl = lane & 15;
    const int kb = (lane >> 4) * 8;

    // ---- stage: issue 10 global_load_lds (2 A + 8 B per thread) for tile k0 ----
    auto stage = [&](int b, int k0) {
        #pragma unroll
        for (int j = 0; j < 2; ++j) {
            int ch  = j * 256 + tid;                 // dest = uniform + lane*16
            int row = ch >> 3;
            int c   = ch & 7;
            gload_lds16(fb + (size_t)(R0 + row) * IN_DIM + k0 + ((c ^ (row & 7)) << 3),
                        &As[b * BM * BK + ch * 8]);
        }
        #pragma unroll
        for (int j = 0; j < 8; ++j) {
            int ch  = j * 256 + tid;
            int kn  = ch >> 9;
            int rem = ch & 511;
            int row = rem >> 3;
            int c   = rem & 7;
            gload_lds16(wb + (size_t)kn * OUT_DIM * IN_DIM + (size_t)(C0 + row) * IN_DIM
                           + k0 + ((c ^ (row & 7)) << 3),
                        &Bs[b * NK * BN * BK + ch * 8]);
        }
    };

    auto compute = [&](int b) {
        const char* Ab = reinterpret_cast<const char*>(As) + b * BM * BK * 2;
        const char* Bb = reinterpret_cast<const char*>(Bs) + b * NK * BN * BK * 2;
        #pragma unroll
        for (int kk = 0; kk < BK; kk += 32) {
            bf16x8 af[2];
            #pragma unroll
            for (int m = 0; m < 2; ++m) {
                int row  = wr + m * 16 + cl;
                int boff = (row * 128 + (kk + kb) * 2) ^ ((row & 7) << 4);
                af[m] = *reinterpret_cast<const bf16x8*>(Ab + boff);
            }
            #pragma unroll
            for (int kn = 0; kn < NK; ++kn) {
                bf16x8 bfr[2];
                #pragma unroll
                for (int n = 0; n < 2; ++n) {
                    int row  = wc + n * 16 + cl;
                    int boff = (row * 128 + (kk + kb) * 2) ^ ((row & 7) << 4);
                    bfr[n] = *reinterpret_cast<const bf16x8*>(Bb + kn * 8192 + boff);
                }
                __builtin_amdgcn_s_setprio(1);
                #pragma unroll
                for (int m = 0; m < 2; ++m)
                    #pragma unroll
                    for (int n = 0; n < 2; ++n)
                        acc[kn][m][n] = __builtin_amdgcn_mfma_f32_16x16x32_bf16(
                            af[m], bfr[n], acc[kn][m][n], 0, 0, 0);
                __builtin_amdgcn_s_setprio(0);
            }
        }
    };

    // ---- prologue: 2-deep prefetch (20 loads in flight per wave) ----
    stage(0, 0);
    stage(1, BK);
    // ---- K-loop: counted vmcnt, raw barriers, never drain to 0 mid-loop ----
    #pragma unroll
    for (int kt = 0; kt < KT; ++kt) {
        const int cur = kt & 1;
        if (kt < KT - 1) asm volatile("s_waitcnt vmcnt(10)" ::: "memory");
        else             asm volatile("s_waitcnt vmcnt(0)"  ::: "memory");
        __builtin_amdgcn_s_barrier();     // all waves' tile-kt loads now visible
        compute(cur);
        __builtin_amdgcn_s_barrier();     // WAR: everyone done reading buffer cur
        if (kt < KT - 2) stage(cur, (kt + 2) * BK);
    }

    // ---- epilogue: res = sum_k p[b,k]*(acc_k + bias_k[o]); elu ----
    const int rl = (lane >> 4) * 4;
    float bcol[2][NK];
    #pragma unroll
    for (int n = 0; n < 2; ++n)
        #pragma unroll
        for (int k = 0; k < NK; ++k)
            bcol[n][k] = bias[k * OUT_DIM + C0 + wc + n * 16 + cl];

    #pragma unroll
    for (int m = 0; m < 2; ++m) {
        #pragma unroll
        for (int r = 0; r < 4; ++r) {
            const int row = R0 + wr + m * 16 + rl + r;
            const float4 p = *reinterpret_cast<const float4*>(&x[(size_t)row * SX + IN_DIM]);
            const float pk[4] = {p.x, p.y, p.z, p.w};
            #pragma unroll
            for (int n = 0; n < 2; ++n) {
                float v = 0.f;
                #pragma unroll
                for (int k = 0; k < NK; ++k)
                    v += pk[k] * (acc[k][m][n][r] + bcol[n][k]);
                v = (v > 0.f) ? v : expm1f(v);
                out[(size_t)row * OUT_DIM + C0 + wc + n * 16 + cl] = v;
            }
        }
    }
}

// ---------------- fallback (round-1 kernel) if ws too small ----------------
#define LDT 72
__global__ __launch_bounds__(256) void mpl_kernel_fb(
    const float* __restrict__ x, const float* __restrict__ w,
    const float* __restrict__ bias, float* __restrict__ out)
{
    __shared__ unsigned short Asf[BM][LDT];
    __shared__ unsigned short Bsf[NK][64][LDT];
    const int tid = threadIdx.x, lane = tid & 63, wid = tid >> 6;
    const int wr = (wid >> 1) * 32, wc = (wid & 1) * 32;
    const int R0 = blockIdx.x * BM, C0 = blockIdx.y * 64;
    f32x4 acc[NK][2][2] = {};
    const int cl = lane & 15, kb = (lane >> 4) * 8;
    for (int kt = 0; kt < KT; ++kt) {
        const int k0 = kt * BK;
        __syncthreads();
        #pragma unroll
        for (int j = 0; j < 4; ++j) {
            int f = tid + 256 * j, row = f >> 4, c4 = (f & 15) * 4;
            const float4 v = *reinterpret_cast<const float4*>(&x[(size_t)(R0 + row) * SX + k0 + c4]);
            unsigned short h[4] = {f2bf(v.x), f2bf(v.y), f2bf(v.z), f2bf(v.w)};
            *reinterpret_cast<uint2*>(&Asf[row][c4]) = *reinterpret_cast<const uint2*>(h);
        }
        #pragma unroll
        for (int kn = 0; kn < NK; ++kn)
            #pragma unroll
            for (int j = 0; j < 4; ++j) {
                int f = tid + 256 * j, row = f >> 4, c4 = (f & 15) * 4;
                const float4 v = *reinterpret_cast<const float4*>(
                    &w[(size_t)kn * OUT_DIM * IN_DIM + (size_t)(C0 + row) * IN_DIM + k0 + c4]);
                unsigned short h[4] = {f2bf(v.x), f2bf(v.y), f2bf(v.z), f2bf(v.w)};
                *reinterpret_cast<uint2*>(&Bsf[kn][row][c4]) = *reinterpret_cast<const uint2*>(h);
            }
        __syncthreads();
        #pragma unroll
        for (int kk = 0; kk < BK; kk += 32) {
            bf16x8 af[2];
            #pragma unroll
            for (int m = 0; m < 2; ++m)
                af[m] = *reinterpret_cast<const bf16x8*>(&Asf[wr + m * 16 + cl][kk + kb]);
            #pragma unroll
            for (int kn = 0; kn < NK; ++kn) {
                bf16x8 bfr[2];
                #pragma unroll
                for (int n = 0; n < 2; ++n)
                    bfr[n] = *reinterpret_cast<const bf16x8*>(&Bsf[kn][wc + n * 16 + cl][kk + kb]);
                #pragma unroll
                for (int m = 0; m < 2; ++m)
                    #pragma unroll
                    for (int n = 0; n < 2; ++n)
                        acc[kn][m][n] = __builtin_amdgcn_mfma_f32_16x16x32_bf16(
                            af[m], bfr[n], acc[kn][m][n], 0, 0, 0);
            }
        }
    }
    const int rl = (lane >> 4) * 4;
    float bcol[2][NK];
    #pragma unroll
    for (int n = 0; n < 2; ++n)
        #pragma unroll
        for (int k = 0; k < NK; ++k)
            bcol[n][k] = bias[k * OUT_DIM + C0 + wc + n * 16 + cl];
    #pragma unroll
    for (int m = 0; m < 2; ++m)
        #pragma unroll
        for (int r = 0; r < 4; ++r) {
            const int row = R0 + wr + m * 16 + rl + r;
            const float4 p = *reinterpret_cast<const float4*>(&x[(size_t)row * SX + IN_DIM]);
            const float pk[4] = {p.x, p.y, p.z, p.w};
            #pragma unroll
            for (int n = 0; n < 2; ++n) {
                float v = 0.f;
                #pragma unroll
                for (int k = 0; k < NK; ++k)
                    v += pk[k] * (acc[k][m][n][r] + bcol[n][k]);
                v = (v > 0.f) ? v : expm1f(v);
                out[(size_t)row * OUT_DIM + C0 + wc + n * 16 + cl] = v;
            }
        }
}

extern "C" void kernel_launch(void* const* d_in, const int* in_sizes, int n_in,
                              void* d_out, int out_size, void* d_ws, size_t ws_size,
                              hipStream_t stream) {
    const float* x    = (const float*)d_in[0];
    const float* w    = (const float*)d_in[1];
    const float* bias = (const float*)d_in[2];
    float* out        = (float*)d_out;

    const size_t wb_bytes = (size_t)NK * OUT_DIM * IN_DIM * 2;   // 2 MB
    const size_t fb_bytes = (size_t)BATCH * IN_DIM * 2;          // 4 MB

    if (ws_size < wb_bytes + fb_bytes) {
        dim3 grid(BATCH / BM, OUT_DIM / 64);
        mpl_kernel_fb<<<grid, dim3(256), 0, stream>>>(x, w, bias, out);
        return;
    }

    unsigned short* wb = (unsigned short*)d_ws;
    unsigned short* fb = (unsigned short*)((char*)d_ws + wb_bytes);

    const int total_chunks = NK * OUT_DIM * IN_DIM / 4 + BATCH * IN_DIM / 4;  // 786432
    convert_kernel<<<dim3(total_chunks / 256), dim3(256), 0, stream>>>(x, w, wb, fb);

    // 1-D grid: (bid & 7) = column tile -> same-column blocks share an XCD's L2
    mpl_gemm<<<dim3((BATCH / BM) * (OUT_DIM / BN)), dim3(256), 0, stream>>>(fb, wb, x, bias, out);
}